// Round 10
// baseline (933.188 us; speedup 1.0000x reference)
//
#include <hip/hip_runtime.h>
#include <hip/hip_bf16.h>
#include <stdint.h>

#define B_    256
#define T_    32
#define V_    10000
#define E_    512
#define H_    512
#define NSTEP 31
#define M_    7936      // NSTEP*B_
#define NG_   2048      // 4*H_
#define VPAD_ 10240
#define SENTU 0x7FC07FC0u   // 2x bf16 NaN sentinel (|h|<1 can never produce it)

typedef __attribute__((ext_vector_type(8))) short  short8;
typedef __attribute__((ext_vector_type(4))) float  f32x4;

static __device__ __forceinline__ unsigned short f2bf(float f) {
  __hip_bfloat16 h = __float2bfloat16(f);
  return *reinterpret_cast<unsigned short*>(&h);
}
static __device__ __forceinline__ ushort4 f4_to_bf4(float4 a) {
  ushort4 r; r.x = f2bf(a.x); r.y = f2bf(a.y); r.z = f2bf(a.z); r.w = f2bf(a.w); return r;
}
// fast gate math: __expf -> v_exp_f32; sigmoid never NaNs (1/(1+inf)=0);
// tanh clamped so exp(-2x) stays finite.
static __device__ __forceinline__ float fsig(float x) {
  return 1.f / (1.f + __expf(-x));
}
static __device__ __forceinline__ float ftanh_(float x) {
  x = fminf(fmaxf(x, -30.f), 30.f);
  float e = __expf(-2.f * x);
  return (1.f - e) / (1.f + e);
}

#define GLOAD_LDS16(gp, lp)                                                                   \
  __builtin_amdgcn_global_load_lds((const __attribute__((address_space(1))) unsigned int*)(gp), \
                                   (__attribute__((address_space(3))) unsigned int*)(lp), 16, 0, 0)

// Coherence-point (bypass L1+L2) access helpers — no cache-maintenance needed.
static __device__ __forceinline__ void store8_cc(void* p, uint2 v) {
  asm volatile("global_store_dwordx2 %0, %1, off sc0 sc1" :: "v"(p), "v"(v) : "memory");
}
static __device__ __forceinline__ uint4 load16_cc(const void* p) {
  uint4 r;
  asm volatile("global_load_dwordx4 %0, %1, off sc0 sc1" : "=v"(r) : "v"(p) : "memory");
  return r;
}

// -------------------------------------------------- weights fp32 -> bf16, bias
__global__ __launch_bounds__(256) void k_prep(
    const float* __restrict__ Wih, const float* __restrict__ Whh,
    const float* __restrict__ Wlin, const float* __restrict__ bih,
    const float* __restrict__ bhh,
    unsigned short* __restrict__ Wihb, unsigned short* __restrict__ Whhb,
    unsigned short* __restrict__ Wlb, float* __restrict__ bias) {
  const int stride = gridDim.x * 256;
  const int i0 = blockIdx.x * 256 + threadIdx.x;
  for (int q = i0; q < (NG_ * E_) / 4; q += stride) {
    ((ushort4*)Wihb)[q] = f4_to_bf4(((const float4*)Wih)[q]);
    ((ushort4*)Whhb)[q] = f4_to_bf4(((const float4*)Whh)[q]);
  }
  for (int q = i0; q < (VPAD_ * H_) / 4; q += stride) {
    int row = q >> 7;  // 128 quads per 512-elem row
    ushort4 r;
    if (row < V_) r = f4_to_bf4(((const float4*)Wlin)[q]);
    else { r.x = 0; r.y = 0; r.z = 0; r.w = 0; }
    ((ushort4*)Wlb)[q] = r;
  }
  for (int q = i0; q < NG_; q += stride) bias[q] = bih[q] + bhh[q];
}

// --- embedding gather -> bf16 X, h0 -> HsAll[0], sentinel-fill HsAll[1..31],
// --- zero out[0]
__global__ __launch_bounds__(256) void k_gather(
    const int* __restrict__ caps, const float* __restrict__ embed,
    const float* __restrict__ latent,
    unsigned short* __restrict__ Xbf, unsigned short* __restrict__ HsAll,
    float* __restrict__ out0) {
  const int stride = gridDim.x * 256;
  const int i0 = blockIdx.x * 256 + threadIdx.x;
  for (int q = i0; q < (M_ * E_) / 4; q += stride) {
    int m = q >> 7;          // row (t*256+b)
    int e4 = q & 127;
    int t = m >> 8, b = m & 255;
    int tok = caps[b * T_ + t];
    float4 a = ((const float4*)(embed + (size_t)tok * E_))[e4];
    ((ushort4*)Xbf)[q] = f4_to_bf4(a);
  }
  for (int q = i0; q < (B_ * H_) / 4; q += stride)
    ((ushort4*)HsAll)[q] = f4_to_bf4(((const float4*)latent)[q]);
  // sentinel-fill slots 1..31 (re-done every call: graph replays don't re-poison)
  uint4 s4 = make_uint4(SENTU, SENTU, SENTU, SENTU);
  uint4* hs1 = (uint4*)(HsAll + (size_t)B_ * H_);
  for (int q = i0; q < (NSTEP * B_ * H_) / 8; q += stride)
    hs1[q] = s4;
  float4 z = make_float4(0.f, 0.f, 0.f, 0.f);
  for (int q = i0; q < (B_ * V_) / 4; q += stride)
    ((float4*)out0)[q] = z;
}

// ---------------------------------------------------- 256x256 bf16 GEMM, BK=64
// A [M,512] bf16 rm, Bt [N,512] bf16 rm (op(B)=B^T), Out fp32 [M,ldo] =
// A*Bt^T + bias. Double-buffered LDS, XOR-swizzled both-sides (rule 21).
template<bool NT>
__global__ __launch_bounds__(512, 2) void gemm256(
    const unsigned short* __restrict__ A, const unsigned short* __restrict__ Bt,
    const float* __restrict__ bias, float* __restrict__ Out, int ldo, int Nvalid) {
  __shared__ unsigned short As[2 * 256 * 64];   // 64 KB
  __shared__ unsigned short Bs[2 * 256 * 64];   // 64 KB
  const int tid = threadIdx.x;
  const int w = tid >> 6, l = tid & 63;
  const int wr = w >> 2, wc = w & 3;

  int flat = blockIdx.y * gridDim.x + blockIdx.x;
  int nwg = gridDim.x * gridDim.y;
  int tile = flat;
  if ((nwg & 7) == 0) { int cpx = nwg >> 3; tile = (flat & 7) * cpx + (flat >> 3); }
  const int bm = tile / gridDim.x, bn = tile % gridDim.x;

  const int srow = (w << 3) + (l >> 3);
  const int schunk = (l & 7) ^ ((l >> 3) & 7);
  const unsigned short* Ab = A + (size_t)(bm * 256 + srow) * 512 + (schunk << 3);
  const unsigned short* Bb = Bt + (size_t)(bn * 256 + srow) * 512 + (schunk << 3);
  unsigned short* Al = As + (w << 9);
  unsigned short* Bl = Bs + (w << 9);

  f32x4 acc[8][4] = {};
  const int lr = l & 15;

#pragma unroll
  for (int i = 0; i < 4; ++i) {
    GLOAD_LDS16(Ab + (size_t)(i << 6) * 512, Al + (i << 12));
    GLOAD_LDS16(Bb + (size_t)(i << 6) * 512, Bl + (i << 12));
  }
  asm volatile("s_waitcnt vmcnt(0)" ::: "memory");
  __syncthreads();

  for (int t = 0; t < 8; ++t) {
    const int cur = (t & 1) << 14;
    if (t < 7) {
      const int nb = ((t & 1) ^ 1) << 14;
      const int k0 = (t + 1) << 6;
#pragma unroll
      for (int i = 0; i < 4; ++i) {
        GLOAD_LDS16(Ab + (size_t)(i << 6) * 512 + k0, Al + nb + (i << 12));
        GLOAD_LDS16(Bb + (size_t)(i << 6) * 512 + k0, Bl + nb + (i << 12));
      }
    }
    const unsigned short* ab = As + cur;
    const unsigned short* bb = Bs + cur;
#pragma unroll
    for (int kc = 0; kc < 2; ++kc) {
      const int cI = (kc << 2) + (l >> 4);
      const int rchunk = (cI ^ (lr & 7)) << 3;
      short8 af[8], bf8[4];
#pragma unroll
      for (int m = 0; m < 8; ++m)
        af[m] = *(const short8*)(ab + ((wr << 7) + (m << 4) + lr) * 64 + rchunk);
#pragma unroll
      for (int n = 0; n < 4; ++n)
        bf8[n] = *(const short8*)(bb + ((wc << 6) + (n << 4) + lr) * 64 + rchunk);
#pragma unroll
      for (int m = 0; m < 8; ++m)
#pragma unroll
        for (int n = 0; n < 4; ++n)
          acc[m][n] = __builtin_amdgcn_mfma_f32_16x16x32_bf16(af[m], bf8[n], acc[m][n], 0, 0, 0);
    }
    asm volatile("s_waitcnt vmcnt(0)" ::: "memory");
    __syncthreads();
  }

  const int orow0 = bm * 256 + (wr << 7) + ((l >> 4) << 2);
  const int ocol0 = bn * 256 + (wc << 6) + lr;
#pragma unroll
  for (int n = 0; n < 4; ++n) {
    int col = ocol0 + (n << 4);
    if (col < Nvalid) {
      float bv = bias[col];
#pragma unroll
      for (int m = 0; m < 8; ++m) {
        int row = orow0 + (m << 4);
#pragma unroll
        for (int r = 0; r < 4; ++r) {
          float v = acc[m][n][r] + bv;
          float* p = &Out[(size_t)(row + r) * ldo + col];
          if (NT) __builtin_nontemporal_store(v, p);
          else    *p = v;
        }
      }
    }
  }
}

// ------------------- persistent fused LSTM chain + logits (sentinel-synced)
// 128 blocks x 256 threads, REGULAR launch: with __launch_bounds__(256,1)
// every block gets >=1 block/CU occupancy; grid 128 <= 256 CUs and the stream
// is serial (GPU idle at dispatch), so all blocks are co-resident — the only
// property the sentinel protocol needs. (r9's cooperative launch was silently
// rejected; its return code is unchecked.)
// Block = (gb = blockIdx>>4: 32 batch rows) x (ct = blockIdx&15: 32 gate-cols
// for the chain, 640 logits cols). Iteration t (0..31): poll+stage h_t
// (sentinel, cc loads) -> [t<31] chain: h_{t+1} = LSTM(h_t), cc-store FIRST
// (unblocks the group) -> [t>=1] logits slice out[t*256+b0..+31][ct*640..+639]
// from the already-verified hsh. Logits in 2 passes x 5 col-blocks, all
// register arrays statically indexed (rule 20). NT stores.
__global__ __launch_bounds__(256, 1) void k_fused(
    const float* __restrict__ Xg,             // [31][256][2048] x@Wih^T + bias
    const unsigned short* __restrict__ Whhb,  // [2048][512] bf16
    const unsigned short* __restrict__ Wlb,   // [10240][512] bf16 (rows>=V_ zero)
    const float* __restrict__ blin,           // [V_]
    unsigned short* __restrict__ HsAll,       // [32][256][512] bf16; slot0 = h0
    float* __restrict__ out) {                // [T*B_][V_] fp32
  __shared__ unsigned short hsh[32 * 512];    // 32 KB, XOR-swizzled chunks
  __shared__ float gsh[4][32 * 32];           // 16 KB
  const int tid = threadIdx.x;
  const int w = tid >> 6, l = tid & 63;
  const int gb = blockIdx.x >> 4;             // batch group 0..7
  const int ct = blockIdx.x & 15;             // col tile 0..15
  const int b0 = gb << 5;
  const int n0 = ct << 5;                     // chain gate-col tile
  const int lr = l & 15;
  const int lk = (l >> 4) << 3;
  const int colw = ct * 640 + w * 160;        // logits col base for this wave

  // ---- Whh fragment base (gate group w, cols n0..n0+31); loads are L2-hot
  const unsigned short* wb0 = Whhb + (size_t)(w * 512 + n0 + lr) * 512 + lk;
  const unsigned short* wb1 = wb0 + (size_t)16 * 512;
  // ---- blin slice (10 cols per lane, fixed for all steps)
  float bl[10];
#pragma unroll
  for (int n = 0; n < 10; ++n) {
    int col = colw + (n << 4) + lr;
    bl[n] = (col < V_) ? blin[col] : 0.f;
  }
  // lane-fixed Wlin base: col (colw+lr), k-subchunk lk
  const unsigned short* wl = Wlb + (size_t)(colw + lr) * 512 + lk;

  float c_reg[4] = {0.f, 0.f, 0.f, 0.f};
  const int br = tid >> 3;
  const int nc0 = (tid & 7) << 2;
  const size_t xg_base = ((size_t)(b0 + br) << 11) + n0 + nc0;

  for (int t = 0; t <= NSTEP; ++t) {
    const bool do_chain = (t < NSTEP);

    // ---- prefetch this step's Xg gate values (latency hides under the poll)
    f32x4 xiv = {}, xfv = {}, xgv = {}, xov = {};
    if (do_chain) {
      const f32x4* xp = (const f32x4*)(Xg + (size_t)t * B_ * NG_ + xg_base);
      xiv = xp[0]; xfv = xp[128]; xgv = xp[256]; xov = xp[384];
    }

    // ---- stage h_t rows b0..b0+31: retry until sentinel-free (data=flag)
    const unsigned short* h_in = HsAll + (size_t)t * B_ * H_;
    uint4 hreg[8];
    int ok;
    do {
#pragma unroll
      for (int j = 0; j < 8; ++j) {
        int row = (j << 2) + w;
        hreg[j] = load16_cc(h_in + (size_t)(b0 + row) * 512 + (l << 3));
      }
      asm volatile("s_waitcnt vmcnt(0)" ::: "memory");
      __builtin_amdgcn_sched_barrier(0);   // keep compares below the wait
      int val = 1;
#pragma unroll
      for (int j = 0; j < 8; ++j) {
        val &= (hreg[j].x != SENTU);
        val &= (hreg[j].y != SENTU);
        val &= (hreg[j].z != SENTU);
        val &= (hreg[j].w != SENTU);
      }
      ok = __syncthreads_and(val);
      if (!ok) __builtin_amdgcn_s_sleep(2);
    } while (!ok);

    // XOR-swizzled LDS write (chunk c of row lands at chunk c^(row&7))
#pragma unroll
    for (int j = 0; j < 8; ++j) {
      int row = (j << 2) + w;
      *(uint4*)(hsh + row * 512 + ((l ^ (row & 7)) << 3)) = hreg[j];
    }
    __syncthreads();

    if (do_chain) {
      // ---- h_t @ Whh^T for this gate group / col tile
      f32x4 acc[2][2] = {};
#pragma unroll
      for (int ks = 0; ks < 16; ++ks) {
        int kc = (ks << 2) + (l >> 4);
        short8 a0 = *(const short8*)(hsh + lr * 512 + ((kc ^ (lr & 7)) << 3));
        short8 a1 = *(const short8*)(hsh + (16 + lr) * 512 + ((kc ^ (lr & 7)) << 3));
        short8 w0 = *(const short8*)(wb0 + (ks << 5));
        short8 w1 = *(const short8*)(wb1 + (ks << 5));
        acc[0][0] = __builtin_amdgcn_mfma_f32_16x16x32_bf16(a0, w0, acc[0][0], 0, 0, 0);
        acc[0][1] = __builtin_amdgcn_mfma_f32_16x16x32_bf16(a0, w1, acc[0][1], 0, 0, 0);
        acc[1][0] = __builtin_amdgcn_mfma_f32_16x16x32_bf16(a1, w0, acc[1][0], 0, 0, 0);
        acc[1][1] = __builtin_amdgcn_mfma_f32_16x16x32_bf16(a1, w1, acc[1][1], 0, 0, 0);
      }

      // ---- gate tiles -> LDS (gate groups live in different waves)
      const int gr0 = (l >> 4) << 2;
#pragma unroll
      for (int m = 0; m < 2; ++m)
#pragma unroll
        for (int n = 0; n < 2; ++n)
#pragma unroll
          for (int r = 0; r < 4; ++r)
            gsh[w][(m * 16 + gr0 + r) * 32 + n * 16 + lr] = acc[m][n][r];
      __syncthreads();

      // ---- cell update + h_{t+1} store (FIRST: unblocks the group's poll)
      f32x4 giv = *(const f32x4*)&gsh[0][(br << 5) + nc0];
      f32x4 gfv = *(const f32x4*)&gsh[1][(br << 5) + nc0];
      f32x4 ggv = *(const f32x4*)&gsh[2][(br << 5) + nc0];
      f32x4 gov = *(const f32x4*)&gsh[3][(br << 5) + nc0];
      ushort4 hv;
      unsigned short* hvp = &hv.x;
#pragma unroll
      for (int j = 0; j < 4; ++j) {
        float is = fsig(giv[j] + xiv[j]);
        float fs = fsig(gfv[j] + xfv[j]);
        float os = fsig(gov[j] + xov[j]);
        float gt = ftanh_(ggv[j] + xgv[j]);
        float cn = fs * c_reg[j] + is * gt;
        c_reg[j] = cn;
        hvp[j] = f2bf(os * ftanh_(cn));
      }
      unsigned short* h_out = HsAll + (size_t)(t + 1) * B_ * H_;
      store8_cc(h_out + ((size_t)(b0 + br) << 9) + n0 + nc0,
                *reinterpret_cast<uint2*>(&hv));
    }

    if (t >= 1) {
      // ---- logits slice: rows t*256+b0..+31, wave cols colw..colw+159,
      // 2 passes x 5 col-blocks; fb0/fb1 double-buffer, static indices only.
      const int r0 = (l >> 4) << 2;
      float* ob = out + (size_t)(t * 256 + b0) * V_;
#pragma unroll
      for (int p = 0; p < 2; ++p) {
        const unsigned short* wlp = wl + (size_t)(p * 80) * 512;
        f32x4 accL[2][5] = {};
        short8 fb0[5], fb1[5];
#pragma unroll
        for (int n = 0; n < 5; ++n)
          fb0[n] = *(const short8*)(wlp + (size_t)(n << 4) * 512);
#pragma unroll
        for (int kk = 0; kk < 8; ++kk) {
          const int ksE = kk << 1, ksO = ksE + 1;
#pragma unroll
          for (int n = 0; n < 5; ++n)
            fb1[n] = *(const short8*)(wlp + (size_t)(n << 4) * 512 + (ksO << 5));
          {
            const int ro = (((ksE << 2) + (l >> 4)) ^ (lr & 7)) << 3;
            short8 a0 = *(const short8*)(hsh + lr * 512 + ro);
            short8 a1 = *(const short8*)(hsh + (16 + lr) * 512 + ro);
#pragma unroll
            for (int n = 0; n < 5; ++n) {
              accL[0][n] = __builtin_amdgcn_mfma_f32_16x16x32_bf16(a0, fb0[n], accL[0][n], 0, 0, 0);
              accL[1][n] = __builtin_amdgcn_mfma_f32_16x16x32_bf16(a1, fb0[n], accL[1][n], 0, 0, 0);
            }
          }
          if (kk < 7) {
#pragma unroll
            for (int n = 0; n < 5; ++n)
              fb0[n] = *(const short8*)(wlp + (size_t)(n << 4) * 512 + ((ksO + 1) << 5));
          }
          {
            const int ro = (((ksO << 2) + (l >> 4)) ^ (lr & 7)) << 3;
            short8 a0 = *(const short8*)(hsh + lr * 512 + ro);
            short8 a1 = *(const short8*)(hsh + (16 + lr) * 512 + ro);
#pragma unroll
            for (int n = 0; n < 5; ++n) {
              accL[0][n] = __builtin_amdgcn_mfma_f32_16x16x32_bf16(a0, fb1[n], accL[0][n], 0, 0, 0);
              accL[1][n] = __builtin_amdgcn_mfma_f32_16x16x32_bf16(a1, fb1[n], accL[1][n], 0, 0, 0);
            }
          }
        }
#pragma unroll
        for (int n = 0; n < 5; ++n) {
          int col = colw + p * 80 + (n << 4) + lr;
          if (col < V_) {
            float bv = bl[p * 5 + n];
#pragma unroll
            for (int m = 0; m < 2; ++m)
#pragma unroll
              for (int r = 0; r < 4; ++r)
                __builtin_nontemporal_store(accL[m][n][r] + bv,
                    ob + (size_t)((m << 4) + r0 + r) * V_ + col);
          }
        }
      }
    }
  }
}

extern "C" void kernel_launch(void* const* d_in, const int* in_sizes, int n_in,
                              void* d_out, int out_size, void* d_ws, size_t ws_size,
                              hipStream_t stream) {
  const int*   caps   = (const int*)d_in[0];
  const float* latent = (const float*)d_in[1];
  const float* embed  = (const float*)d_in[2];
  const float* Wih    = (const float*)d_in[3];
  const float* Whh    = (const float*)d_in[4];
  const float* bih    = (const float*)d_in[5];
  const float* bhh    = (const float*)d_in[6];
  const float* Wlin   = (const float*)d_in[7];
  const float* blin   = (const float*)d_in[8];
  float* out = (float*)d_out;

  char* ws = (char*)d_ws;
  size_t off = 0;
  auto alloc = [&](size_t bytes) {
    void* p = ws + off;
    off = (off + bytes + 255) & ~(size_t)255;
    return p;
  };
  unsigned short* Xbf   = (unsigned short*)alloc((size_t)M_ * E_ * 2);
  unsigned short* Wihb  = (unsigned short*)alloc((size_t)NG_ * E_ * 2);
  unsigned short* Whhb  = (unsigned short*)alloc((size_t)NG_ * H_ * 2);
  unsigned short* Wlb   = (unsigned short*)alloc((size_t)VPAD_ * H_ * 2);
  float*          bias  = (float*)alloc((size_t)NG_ * 4);
  float*          Xg    = (float*)alloc((size_t)M_ * NG_ * 4);
  unsigned short* HsAll = (unsigned short*)alloc((size_t)(NSTEP + 1) * B_ * H_ * 2);
  (void)ws_size; (void)in_sizes; (void)n_in; (void)out_size;

  hipLaunchKernelGGL(k_prep, dim3(2048), dim3(256), 0, stream,
                     Wih, Whh, Wlin, bih, bhh, Wihb, Whhb, Wlb, bias);
  hipLaunchKernelGGL(k_gather, dim3(2048), dim3(256), 0, stream,
                     caps, embed, latent, Xbf, HsAll, out);
  // Xg = X @ Wih^T + bias   [7936 x 2048]  (normal stores: chain re-reads Xg)
  hipLaunchKernelGGL((gemm256<false>), dim3(NG_ / 256, M_ / 256), dim3(512), 0, stream,
                     Xbf, Wihb, bias, Xg, NG_, NG_);
  // persistent fused LSTM chain + logits — regular launch (co-residency by
  // construction: 128 blocks <= 256 CUs at >=1 block/CU, serial stream)
  hipLaunchKernelGGL(k_fused, dim3(128), dim3(256), 0, stream,
                     Xg, Whhb, Wlb, blin, HsAll, out);
}

// Round 11
// 278.963 us; speedup vs baseline: 3.3452x; 3.3452x over previous
//
#include <hip/hip_runtime.h>
#include <hip/hip_bf16.h>
#include <stdint.h>

#define B_    256
#define T_    32
#define V_    10000
#define E_    512
#define H_    512
#define NSTEP 31
#define M_    7936      // NSTEP*B_
#define NG_   2048      // 4*H_
#define VPAD_ 10240
#define SENTU 0x7FC07FC0u   // 2x bf16 NaN sentinel (|h|<1 can never produce it)

typedef __attribute__((ext_vector_type(8))) short  short8;
typedef __attribute__((ext_vector_type(4))) float  f32x4;

static __device__ __forceinline__ unsigned short f2bf(float f) {
  __hip_bfloat16 h = __float2bfloat16(f);
  return *reinterpret_cast<unsigned short*>(&h);
}
static __device__ __forceinline__ ushort4 f4_to_bf4(float4 a) {
  ushort4 r; r.x = f2bf(a.x); r.y = f2bf(a.y); r.z = f2bf(a.z); r.w = f2bf(a.w); return r;
}
static __device__ __forceinline__ float fsig(float x) {
  return 1.f / (1.f + __expf(-x));
}
static __device__ __forceinline__ float ftanh_(float x) {
  x = fminf(fmaxf(x, -30.f), 30.f);
  float e = __expf(-2.f * x);
  return (1.f - e) / (1.f + e);
}

#define GLOAD_LDS16(gp, lp)                                                                   \
  __builtin_amdgcn_global_load_lds((const __attribute__((address_space(1))) unsigned int*)(gp), \
                                   (__attribute__((address_space(3))) unsigned int*)(lp), 16, 0, 0)

// Coherence-point (bypass L1+L2) access helpers.
static __device__ __forceinline__ void store8_cc(void* p, uint2 v) {
  asm volatile("global_store_dwordx2 %0, %1, off sc0 sc1" :: "v"(p), "v"(v) : "memory");
}
static __device__ __forceinline__ uint4 load16_cc(const void* p) {
  uint4 r;
  asm volatile("global_load_dwordx4 %0, %1, off sc0 sc1" : "=v"(r) : "v"(p) : "memory");
  return r;
}

// -------------------------------------------------- weights fp32 -> bf16, bias
__global__ __launch_bounds__(256) void k_prep(
    const float* __restrict__ Wih, const float* __restrict__ Whh,
    const float* __restrict__ Wlin, const float* __restrict__ bih,
    const float* __restrict__ bhh,
    unsigned short* __restrict__ Wihb, unsigned short* __restrict__ Whhb,
    unsigned short* __restrict__ Wlb, float* __restrict__ bias) {
  const int stride = gridDim.x * 256;
  const int i0 = blockIdx.x * 256 + threadIdx.x;
  for (int q = i0; q < (NG_ * E_) / 4; q += stride) {
    ((ushort4*)Wihb)[q] = f4_to_bf4(((const float4*)Wih)[q]);
    ((ushort4*)Whhb)[q] = f4_to_bf4(((const float4*)Whh)[q]);
  }
  for (int q = i0; q < (VPAD_ * H_) / 4; q += stride) {
    int row = q >> 7;
    ushort4 r;
    if (row < V_) r = f4_to_bf4(((const float4*)Wlin)[q]);
    else { r.x = 0; r.y = 0; r.z = 0; r.w = 0; }
    ((ushort4*)Wlb)[q] = r;
  }
  for (int q = i0; q < NG_; q += stride) bias[q] = bih[q] + bhh[q];
}

// --- embedding gather -> bf16 X, h0 -> HsAll[0], sentinel-fill HsAll[1..31],
// --- zero out[0]
__global__ __launch_bounds__(256) void k_gather(
    const int* __restrict__ caps, const float* __restrict__ embed,
    const float* __restrict__ latent,
    unsigned short* __restrict__ Xbf, unsigned short* __restrict__ HsAll,
    float* __restrict__ out0) {
  const int stride = gridDim.x * 256;
  const int i0 = blockIdx.x * 256 + threadIdx.x;
  for (int q = i0; q < (M_ * E_) / 4; q += stride) {
    int m = q >> 7;
    int e4 = q & 127;
    int t = m >> 8, b = m & 255;
    int tok = caps[b * T_ + t];
    float4 a = ((const float4*)(embed + (size_t)tok * E_))[e4];
    ((ushort4*)Xbf)[q] = f4_to_bf4(a);
  }
  for (int q = i0; q < (B_ * H_) / 4; q += stride)
    ((ushort4*)HsAll)[q] = f4_to_bf4(((const float4*)latent)[q]);
  uint4 s4 = make_uint4(SENTU, SENTU, SENTU, SENTU);
  uint4* hs1 = (uint4*)(HsAll + (size_t)B_ * H_);
  for (int q = i0; q < (NSTEP * B_ * H_) / 8; q += stride)
    hs1[q] = s4;
  float4 z = make_float4(0.f, 0.f, 0.f, 0.f);
  for (int q = i0; q < (B_ * V_) / 4; q += stride)
    ((float4*)out0)[q] = z;
}

// ---------------------------------------------------- 256x256 bf16 GEMM, BK=64
// (used for Xg only). Double-buffered LDS, XOR-swizzled both-sides.
template<bool NT>
__global__ __launch_bounds__(512, 2) void gemm256(
    const unsigned short* __restrict__ A, const unsigned short* __restrict__ Bt,
    const float* __restrict__ bias, float* __restrict__ Out, int ldo, int Nvalid) {
  __shared__ unsigned short As[2 * 256 * 64];
  __shared__ unsigned short Bs[2 * 256 * 64];
  const int tid = threadIdx.x;
  const int w = tid >> 6, l = tid & 63;
  const int wr = w >> 2, wc = w & 3;

  int flat = blockIdx.y * gridDim.x + blockIdx.x;
  int nwg = gridDim.x * gridDim.y;
  int tile = flat;
  if ((nwg & 7) == 0) { int cpx = nwg >> 3; tile = (flat & 7) * cpx + (flat >> 3); }
  const int bm = tile / gridDim.x, bn = tile % gridDim.x;

  const int srow = (w << 3) + (l >> 3);
  const int schunk = (l & 7) ^ ((l >> 3) & 7);
  const unsigned short* Ab = A + (size_t)(bm * 256 + srow) * 512 + (schunk << 3);
  const unsigned short* Bb = Bt + (size_t)(bn * 256 + srow) * 512 + (schunk << 3);
  unsigned short* Al = As + (w << 9);
  unsigned short* Bl = Bs + (w << 9);

  f32x4 acc[8][4] = {};
  const int lr = l & 15;

#pragma unroll
  for (int i = 0; i < 4; ++i) {
    GLOAD_LDS16(Ab + (size_t)(i << 6) * 512, Al + (i << 12));
    GLOAD_LDS16(Bb + (size_t)(i << 6) * 512, Bl + (i << 12));
  }
  asm volatile("s_waitcnt vmcnt(0)" ::: "memory");
  __syncthreads();

  for (int t = 0; t < 8; ++t) {
    const int cur = (t & 1) << 14;
    if (t < 7) {
      const int nb = ((t & 1) ^ 1) << 14;
      const int k0 = (t + 1) << 6;
#pragma unroll
      for (int i = 0; i < 4; ++i) {
        GLOAD_LDS16(Ab + (size_t)(i << 6) * 512 + k0, Al + nb + (i << 12));
        GLOAD_LDS16(Bb + (size_t)(i << 6) * 512 + k0, Bl + nb + (i << 12));
      }
    }
    const unsigned short* ab = As + cur;
    const unsigned short* bb = Bs + cur;
#pragma unroll
    for (int kc = 0; kc < 2; ++kc) {
      const int cI = (kc << 2) + (l >> 4);
      const int rchunk = (cI ^ (lr & 7)) << 3;
      short8 af[8], bf8[4];
#pragma unroll
      for (int m = 0; m < 8; ++m)
        af[m] = *(const short8*)(ab + ((wr << 7) + (m << 4) + lr) * 64 + rchunk);
#pragma unroll
      for (int n = 0; n < 4; ++n)
        bf8[n] = *(const short8*)(bb + ((wc << 6) + (n << 4) + lr) * 64 + rchunk);
#pragma unroll
      for (int m = 0; m < 8; ++m)
#pragma unroll
        for (int n = 0; n < 4; ++n)
          acc[m][n] = __builtin_amdgcn_mfma_f32_16x16x32_bf16(af[m], bf8[n], acc[m][n], 0, 0, 0);
    }
    asm volatile("s_waitcnt vmcnt(0)" ::: "memory");
    __syncthreads();
  }

  const int orow0 = bm * 256 + (wr << 7) + ((l >> 4) << 2);
  const int ocol0 = bn * 256 + (wc << 6) + lr;
#pragma unroll
  for (int n = 0; n < 4; ++n) {
    int col = ocol0 + (n << 4);
    if (col < Nvalid) {
      float bv = bias[col];
#pragma unroll
      for (int m = 0; m < 8; ++m) {
        int row = orow0 + (m << 4);
#pragma unroll
        for (int r = 0; r < 4; ++r) {
          float v = acc[m][n][r] + bv;
          float* p = &Out[(size_t)(row + r) * ldo + col];
          if (NT) __builtin_nontemporal_store(v, p);
          else    *p = v;
        }
      }
    }
  }
}

// ---------------- mixed-role kernel: 64 chain blocks + 1240 logits blocks
// 512 threads. blockIdx 0..63: persistent LSTM chain (sentinel-synced, as
// before but 8 blocks/group x 64 cols). blockIdx 64..: one 256x256 logits
// tile (t = idx/40+1 ascending so resident blocks target earliest steps,
// bn = idx%40). Logits A (h_t) is sentinel-verified reg-staging; B (Wlin)
// via global_load_lds with pre-swizzled source. Chain never waits on logits
// => no deadlock. LDS = 64KB union of both roles.
__global__ __launch_bounds__(512, 2) void k_mix(
    const float* __restrict__ Xg,             // [31][256][2048]
    const unsigned short* __restrict__ Whhb,  // [2048][512] bf16
    const unsigned short* __restrict__ Wlb,   // [10240][512] bf16
    const float* __restrict__ blin,           // [V_]
    unsigned short* __restrict__ HsAll,       // [32][256][512] bf16; slot0=h0
    float* __restrict__ out) {                // [T*B_][V_] fp32
  __shared__ uint4 smem_raw[65536 / 16];      // 64 KB, 16B aligned
  const int tid = threadIdx.x;
  const int w = tid >> 6, l = tid & 63;
  const int lr = l & 15;

  if (blockIdx.x < 64) {
    // ================= chain role =================
    unsigned short* hsh = (unsigned short*)smem_raw;           // [32][512] 32KB
    float* gsh = (float*)((char*)smem_raw + 32768);            // [4][32*64] 32KB
    const int gb = blockIdx.x & 7;     // group (same-XCD heuristic)
    const int ct = blockIdx.x >> 3;    // col tile 0..7 (64 cols)
    const int b0 = gb << 5;
    const int n0 = ct << 6;
    const int g  = w >> 1;             // gate 0..3
    const int cs = (w & 1) << 5;       // col-sub 0/32
    const int lk = (l >> 4) << 3;

    // Whh fragments for wave's 32 cols stay in VGPRs
    short8 bf0[16], bf1[16];
    {
      const unsigned short* wb0 = Whhb + (size_t)(g * 512 + n0 + cs + lr) * 512 + lk;
      const unsigned short* wb1 = wb0 + (size_t)16 * 512;
#pragma unroll 16
      for (int ks = 0; ks < 16; ++ks) {
        bf0[ks] = *(const short8*)(wb0 + (ks << 5));
        bf1[ks] = *(const short8*)(wb1 + (ks << 5));
      }
    }
    float c_reg[4] = {0.f, 0.f, 0.f, 0.f};
    const int br  = tid >> 4;          // update row 0..31
    const int nc0 = (tid & 15) << 2;   // update col base 0..60
    const size_t xg_base = ((size_t)(b0 + br) << 11) + n0 + nc0;
    const int srow = tid >> 4;         // staging row 0..31
    const int scb  = (tid & 15) << 2;  // staging chunk base (16B units)

    for (int t = 0; t < NSTEP; ++t) {
      const f32x4* xp = (const f32x4*)(Xg + (size_t)t * B_ * NG_ + xg_base);
      f32x4 xiv = xp[0], xfv = xp[128], xgv = xp[256], xov = xp[384];

      const unsigned short* h_in = HsAll + (size_t)t * B_ * H_;
      uint4 hreg[4];
      int ok;
      do {
#pragma unroll
        for (int j = 0; j < 4; ++j)
          hreg[j] = load16_cc(h_in + (size_t)(b0 + srow) * 512 + ((scb + j) << 3));
        asm volatile("s_waitcnt vmcnt(0)" ::: "memory");
        __builtin_amdgcn_sched_barrier(0);
        int val = 1;
#pragma unroll
        for (int j = 0; j < 4; ++j) {
          val &= (hreg[j].x != SENTU); val &= (hreg[j].y != SENTU);
          val &= (hreg[j].z != SENTU); val &= (hreg[j].w != SENTU);
        }
        ok = __syncthreads_and(val);
        if (!ok) __builtin_amdgcn_s_sleep(2);
      } while (!ok);
#pragma unroll
      for (int j = 0; j < 4; ++j) {
        int cb = scb + j;
        *(uint4*)(hsh + srow * 512 + ((cb ^ (srow & 7)) << 3)) = hreg[j];
      }
      __syncthreads();

      f32x4 acc[2][2] = {};
#pragma unroll
      for (int ks = 0; ks < 16; ++ks) {
        int kc = (ks << 2) + (l >> 4);
        short8 a0 = *(const short8*)(hsh + lr * 512 + ((kc ^ (lr & 7)) << 3));
        short8 a1 = *(const short8*)(hsh + (16 + lr) * 512 + ((kc ^ (lr & 7)) << 3));
        acc[0][0] = __builtin_amdgcn_mfma_f32_16x16x32_bf16(a0, bf0[ks], acc[0][0], 0, 0, 0);
        acc[0][1] = __builtin_amdgcn_mfma_f32_16x16x32_bf16(a0, bf1[ks], acc[0][1], 0, 0, 0);
        acc[1][0] = __builtin_amdgcn_mfma_f32_16x16x32_bf16(a1, bf0[ks], acc[1][0], 0, 0, 0);
        acc[1][1] = __builtin_amdgcn_mfma_f32_16x16x32_bf16(a1, bf1[ks], acc[1][1], 0, 0, 0);
      }

      // gate tile -> gsh[g], rows 0..31 x cols cs..cs+31
      const int gr0 = (l >> 4) << 2;
#pragma unroll
      for (int m = 0; m < 2; ++m)
#pragma unroll
        for (int n = 0; n < 2; ++n)
#pragma unroll
          for (int r = 0; r < 4; ++r)
            gsh[g * 2048 + (m * 16 + gr0 + r) * 64 + cs + n * 16 + lr] = acc[m][n][r];
      __syncthreads();

      f32x4 giv = *(const f32x4*)&gsh[0 * 2048 + br * 64 + nc0];
      f32x4 gfv = *(const f32x4*)&gsh[1 * 2048 + br * 64 + nc0];
      f32x4 ggv = *(const f32x4*)&gsh[2 * 2048 + br * 64 + nc0];
      f32x4 gov = *(const f32x4*)&gsh[3 * 2048 + br * 64 + nc0];
      ushort4 hv; unsigned short* hvp = &hv.x;
#pragma unroll
      for (int j = 0; j < 4; ++j) {
        float is = fsig(giv[j] + xiv[j]);
        float fs = fsig(gfv[j] + xfv[j]);
        float os = fsig(gov[j] + xov[j]);
        float gt = ftanh_(ggv[j] + xgv[j]);
        float cn = fs * c_reg[j] + is * gt;
        c_reg[j] = cn;
        hvp[j] = f2bf(os * ftanh_(cn));
      }
      unsigned short* h_out = HsAll + (size_t)(t + 1) * B_ * H_;
      store8_cc(h_out + ((size_t)(b0 + br) << 9) + n0 + nc0,
                *reinterpret_cast<uint2*>(&hv));
      // no drain/fence/flag: data IS the flag.
    }
  } else {
    // ================= logits role =================
    unsigned short* As = (unsigned short*)smem_raw;            // [256][64] 32KB
    unsigned short* Bs = (unsigned short*)((char*)smem_raw + 32768);
    const int idx = blockIdx.x - 64;
    const int t  = idx / 40 + 1;       // 1..31, ascending with blockIdx
    const int bn = idx % 40;
    const unsigned short* slotT = HsAll + (size_t)t * B_ * H_;

    // B staging (gload_lds, linear dest + pre-swizzled source)
    const int srowB = (w << 3) + (l >> 3);
    const int schB  = (l & 7) ^ ((l >> 3) & 7);
    const unsigned short* Bb = Wlb + (size_t)(bn * 256 + srowB) * 512 + (schB << 3);
    unsigned short* Bl = Bs + (w << 9);
    // A staging: thread -> row tid>>1, chunkbase (tid&1)*4
    const int rA  = tid >> 1;
    const int cbA = (tid & 1) << 2;
    const unsigned short* Ab = slotT + (size_t)rA * 512;
    const int wr = w >> 2, wc = w & 3;

    f32x4 acc[8][4] = {};
    for (int kt = 0; kt < 8; ++kt) {
      const int k0 = kt << 6;
#pragma unroll
      for (int i = 0; i < 4; ++i)
        GLOAD_LDS16(Bb + (size_t)(i << 6) * 512 + k0, Bl + (i << 12));

      uint4 ar[4]; int ok;
      do {
#pragma unroll
        for (int j = 0; j < 4; ++j)
          ar[j] = load16_cc(Ab + k0 + ((cbA + j) << 3));
        asm volatile("s_waitcnt vmcnt(0)" ::: "memory");   // also drains B
        __builtin_amdgcn_sched_barrier(0);
        int val = 1;
#pragma unroll
        for (int j = 0; j < 4; ++j) {
          val &= (ar[j].x != SENTU); val &= (ar[j].y != SENTU);
          val &= (ar[j].z != SENTU); val &= (ar[j].w != SENTU);
        }
        ok = __syncthreads_and(val);
        if (!ok) __builtin_amdgcn_s_sleep(8);
      } while (!ok);
#pragma unroll
      for (int j = 0; j < 4; ++j) {
        int cb = cbA + j;
        *(uint4*)(As + rA * 64 + ((cb ^ (rA & 7)) << 3)) = ar[j];
      }
      __syncthreads();

#pragma unroll
      for (int ksub = 0; ksub < 2; ++ksub) {
        const int cI = (ksub << 2) + (l >> 4);
        const int ro = (cI ^ (lr & 7)) << 3;
        short8 af[8], bf8[4];
#pragma unroll
        for (int m = 0; m < 8; ++m)
          af[m] = *(const short8*)(As + ((wr << 7) + (m << 4) + lr) * 64 + ro);
#pragma unroll
        for (int n = 0; n < 4; ++n)
          bf8[n] = *(const short8*)(Bs + ((wc << 6) + (n << 4) + lr) * 64 + ro);
#pragma unroll
        for (int m = 0; m < 8; ++m)
#pragma unroll
          for (int n = 0; n < 4; ++n)
            acc[m][n] = __builtin_amdgcn_mfma_f32_16x16x32_bf16(af[m], bf8[n], acc[m][n], 0, 0, 0);
      }
      __syncthreads();
    }

    const int orow0 = t * 256 + (wr << 7) + ((l >> 4) << 2);
    const int ocol0 = bn * 256 + (wc << 6) + lr;
#pragma unroll
    for (int n = 0; n < 4; ++n) {
      int col = ocol0 + (n << 4);
      if (col < V_) {
        float bv = blin[col];
#pragma unroll
        for (int m = 0; m < 8; ++m) {
          int row = orow0 + (m << 4);
#pragma unroll
          for (int r = 0; r < 4; ++r)
            __builtin_nontemporal_store(acc[m][n][r] + bv,
                &out[(size_t)(row + r) * V_ + col]);
        }
      }
    }
  }
}

extern "C" void kernel_launch(void* const* d_in, const int* in_sizes, int n_in,
                              void* d_out, int out_size, void* d_ws, size_t ws_size,
                              hipStream_t stream) {
  const int*   caps   = (const int*)d_in[0];
  const float* latent = (const float*)d_in[1];
  const float* embed  = (const float*)d_in[2];
  const float* Wih    = (const float*)d_in[3];
  const float* Whh    = (const float*)d_in[4];
  const float* bih    = (const float*)d_in[5];
  const float* bhh    = (const float*)d_in[6];
  const float* Wlin   = (const float*)d_in[7];
  const float* blin   = (const float*)d_in[8];
  float* out = (float*)d_out;

  char* ws = (char*)d_ws;
  size_t off = 0;
  auto alloc = [&](size_t bytes) {
    void* p = ws + off;
    off = (off + bytes + 255) & ~(size_t)255;
    return p;
  };
  unsigned short* Xbf   = (unsigned short*)alloc((size_t)M_ * E_ * 2);
  unsigned short* Wihb  = (unsigned short*)alloc((size_t)NG_ * E_ * 2);
  unsigned short* Whhb  = (unsigned short*)alloc((size_t)NG_ * H_ * 2);
  unsigned short* Wlb   = (unsigned short*)alloc((size_t)VPAD_ * H_ * 2);
  float*          bias  = (float*)alloc((size_t)NG_ * 4);
  float*          Xg    = (float*)alloc((size_t)M_ * NG_ * 4);
  unsigned short* HsAll = (unsigned short*)alloc((size_t)(NSTEP + 1) * B_ * H_ * 2);
  (void)ws_size; (void)in_sizes; (void)n_in; (void)out_size;

  hipLaunchKernelGGL(k_prep, dim3(2048), dim3(256), 0, stream,
                     Wih, Whh, Wlin, bih, bhh, Wihb, Whhb, Wlb, bias);
  hipLaunchKernelGGL(k_gather, dim3(2048), dim3(256), 0, stream,
                     caps, embed, latent, Xbf, HsAll, out);
  // Xg = X @ Wih^T + bias   [7936 x 2048]
  hipLaunchKernelGGL((gemm256<false>), dim3(NG_ / 256, M_ / 256), dim3(512), 0, stream,
                     Xbf, Wihb, bias, Xg, NG_, NG_);
  // mixed chain + logits kernel: 64 chain blocks (first, co-resident) +
  // 31*40 logits tiles in t-ascending order.
  hipLaunchKernelGGL(k_mix, dim3(64 + NSTEP * 40), dim3(512), 0, stream,
                     Xg, Whhb, Wlb, blin, HsAll, out);
}

// Round 12
// 224.710 us; speedup vs baseline: 4.1529x; 1.2414x over previous
//
#include <hip/hip_runtime.h>
#include <hip/hip_bf16.h>
#include <stdint.h>

#define B_    256
#define T_    32
#define V_    10000
#define E_    512
#define H_    512
#define NSTEP 31
#define M_    7936      // NSTEP*B_
#define NG_   2048      // 4*H_
#define VPAD_ 10240

typedef __attribute__((ext_vector_type(8))) short  short8;
typedef __attribute__((ext_vector_type(4))) float  f32x4;

static __device__ __forceinline__ unsigned short f2bf(float f) {
  __hip_bfloat16 h = __float2bfloat16(f);
  return *reinterpret_cast<unsigned short*>(&h);
}
static __device__ __forceinline__ ushort4 f4_to_bf4(float4 a) {
  ushort4 r; r.x = f2bf(a.x); r.y = f2bf(a.y); r.z = f2bf(a.z); r.w = f2bf(a.w); return r;
}
static __device__ __forceinline__ float fsig(float x) {
  return 1.f / (1.f + __expf(-x));
}
static __device__ __forceinline__ float ftanh_(float x) {
  x = fminf(fmaxf(x, -30.f), 30.f);
  float e = __expf(-2.f * x);
  return (1.f - e) / (1.f + e);
}

#define GLOAD_LDS16(gp, lp)                                                                   \
  __builtin_amdgcn_global_load_lds((const __attribute__((address_space(1))) unsigned int*)(gp), \
                                   (__attribute__((address_space(3))) unsigned int*)(lp), 16, 0, 0)

// Coherence-point store (bypass L1+L2): producer h stores must be visible to
// other XCDs once the step counter is bumped (counter add happens after a full
// vmcnt drain, so flag-visible => data-at-coherence-point).
static __device__ __forceinline__ void store8_cc(void* p, uint2 v) {
  asm volatile("global_store_dwordx2 %0, %1, off sc0 sc1" :: "v"(p), "v"(v) : "memory");
}

// -------------------------------------------------- weights fp32 -> bf16, bias
__global__ __launch_bounds__(256) void k_prep(
    const float* __restrict__ Wih, const float* __restrict__ Whh,
    const float* __restrict__ Wlin, const float* __restrict__ bih,
    const float* __restrict__ bhh,
    unsigned short* __restrict__ Wihb, unsigned short* __restrict__ Whhb,
    unsigned short* __restrict__ Wlb, float* __restrict__ bias) {
  const int stride = gridDim.x * 256;
  const int i0 = blockIdx.x * 256 + threadIdx.x;
  for (int q = i0; q < (NG_ * E_) / 4; q += stride) {
    ((ushort4*)Wihb)[q] = f4_to_bf4(((const float4*)Wih)[q]);
    ((ushort4*)Whhb)[q] = f4_to_bf4(((const float4*)Whh)[q]);
  }
  for (int q = i0; q < (VPAD_ * H_) / 4; q += stride) {
    int row = q >> 7;
    ushort4 r;
    if (row < V_) r = f4_to_bf4(((const float4*)Wlin)[q]);
    else { r.x = 0; r.y = 0; r.z = 0; r.w = 0; }
    ((ushort4*)Wlb)[q] = r;
  }
  for (int q = i0; q < NG_; q += stride) bias[q] = bih[q] + bhh[q];
}

// --- embedding gather -> bf16 X, h0 -> HsAll[0], zero out[0] + counters
__global__ __launch_bounds__(256) void k_gather(
    const int* __restrict__ caps, const float* __restrict__ embed,
    const float* __restrict__ latent,
    unsigned short* __restrict__ Xbf, unsigned short* __restrict__ HsAll,
    float* __restrict__ out0, int* __restrict__ cnt) {
  const int stride = gridDim.x * 256;
  const int i0 = blockIdx.x * 256 + threadIdx.x;
  for (int q = i0; q < (M_ * E_) / 4; q += stride) {
    int m = q >> 7;
    int e4 = q & 127;
    int t = m >> 8, b = m & 255;
    int tok = caps[b * T_ + t];
    float4 a = ((const float4*)(embed + (size_t)tok * E_))[e4];
    ((ushort4*)Xbf)[q] = f4_to_bf4(a);
  }
  for (int q = i0; q < (B_ * H_) / 4; q += stride)
    ((ushort4*)HsAll)[q] = f4_to_bf4(((const float4*)latent)[q]);
  float4 z = make_float4(0.f, 0.f, 0.f, 0.f);
  for (int q = i0; q < (B_ * V_) / 4; q += stride)
    ((float4*)out0)[q] = z;
  if (blockIdx.x == 0 && threadIdx.x < 32 * 8)
    cnt[threadIdx.x] = 0;                     // cnt[t][g], re-zeroed every call
}

// ---------------------------------------------------- 256x256 bf16 GEMM, BK=64
// (used for Xg). Double-buffered LDS, XOR-swizzled both-sides.
template<bool NT>
__global__ __launch_bounds__(512, 2) void gemm256(
    const unsigned short* __restrict__ A, const unsigned short* __restrict__ Bt,
    const float* __restrict__ bias, float* __restrict__ Out, int ldo, int Nvalid) {
  __shared__ unsigned short As[2 * 256 * 64];
  __shared__ unsigned short Bs[2 * 256 * 64];
  const int tid = threadIdx.x;
  const int w = tid >> 6, l = tid & 63;
  const int wr = w >> 2, wc = w & 3;

  int flat = blockIdx.y * gridDim.x + blockIdx.x;
  int nwg = gridDim.x * gridDim.y;
  int tile = flat;
  if ((nwg & 7) == 0) { int cpx = nwg >> 3; tile = (flat & 7) * cpx + (flat >> 3); }
  const int bm = tile / gridDim.x, bn = tile % gridDim.x;

  const int srow = (w << 3) + (l >> 3);
  const int schunk = (l & 7) ^ ((l >> 3) & 7);
  const unsigned short* Ab = A + (size_t)(bm * 256 + srow) * 512 + (schunk << 3);
  const unsigned short* Bb = Bt + (size_t)(bn * 256 + srow) * 512 + (schunk << 3);
  unsigned short* Al = As + (w << 9);
  unsigned short* Bl = Bs + (w << 9);

  f32x4 acc[8][4] = {};
  const int lr = l & 15;

#pragma unroll
  for (int i = 0; i < 4; ++i) {
    GLOAD_LDS16(Ab + (size_t)(i << 6) * 512, Al + (i << 12));
    GLOAD_LDS16(Bb + (size_t)(i << 6) * 512, Bl + (i << 12));
  }
  asm volatile("s_waitcnt vmcnt(0)" ::: "memory");
  __syncthreads();

  for (int t = 0; t < 8; ++t) {
    const int cur = (t & 1) << 14;
    if (t < 7) {
      const int nb = ((t & 1) ^ 1) << 14;
      const int k0 = (t + 1) << 6;
#pragma unroll
      for (int i = 0; i < 4; ++i) {
        GLOAD_LDS16(Ab + (size_t)(i << 6) * 512 + k0, Al + nb + (i << 12));
        GLOAD_LDS16(Bb + (size_t)(i << 6) * 512 + k0, Bl + nb + (i << 12));
      }
    }
    const unsigned short* ab = As + cur;
    const unsigned short* bb = Bs + cur;
#pragma unroll
    for (int kc = 0; kc < 2; ++kc) {
      const int cI = (kc << 2) + (l >> 4);
      const int rchunk = (cI ^ (lr & 7)) << 3;
      short8 af[8], bf8[4];
#pragma unroll
      for (int m = 0; m < 8; ++m)
        af[m] = *(const short8*)(ab + ((wr << 7) + (m << 4) + lr) * 64 + rchunk);
#pragma unroll
      for (int n = 0; n < 4; ++n)
        bf8[n] = *(const short8*)(bb + ((wc << 6) + (n << 4) + lr) * 64 + rchunk);
#pragma unroll
      for (int m = 0; m < 8; ++m)
#pragma unroll
        for (int n = 0; n < 4; ++n)
          acc[m][n] = __builtin_amdgcn_mfma_f32_16x16x32_bf16(af[m], bf8[n], acc[m][n], 0, 0, 0);
    }
    asm volatile("s_waitcnt vmcnt(0)" ::: "memory");
    __syncthreads();
  }

  const int orow0 = bm * 256 + (wr << 7) + ((l >> 4) << 2);
  const int ocol0 = bn * 256 + (wc << 6) + lr;
#pragma unroll
  for (int n = 0; n < 4; ++n) {
    int col = ocol0 + (n << 4);
    if (col < Nvalid) {
      float bv = bias[col];
#pragma unroll
      for (int m = 0; m < 8; ++m) {
        int row = orow0 + (m << 4);
#pragma unroll
        for (int r = 0; r < 4; ++r) {
          float v = acc[m][n][r] + bv;
          float* p = &Out[(size_t)(row + r) * ldo + col];
          if (NT) __builtin_nontemporal_store(v, p);
          else    *p = v;
        }
      }
    }
  }
}

// ---------------- mixed-role kernel: 64 chain blocks + 1240 logits blocks
// 512 threads, 128KB LDS => 1 block/CU: chain blocks own their CU exclusively
// (r11's regression was logits co-residents contending on chain CUs).
// Sync = per-(step,group) arrival counters cnt[t][g] (relaxed atomics, no
// fences): producer drains vmcnt THEN adds, so counter-visible => h data at
// the coherence point; consumers first-touch slot t only after the gate, so
// no stale-L2 copies can exist and CACHED loads (incl. global_load_lds) are
// legal for h. Chain role gates on own group (4B poll); logits role gates on
// all 8 groups, then runs the full double-buffered gemm256 pipeline.
__global__ __launch_bounds__(512, 2) void k_mix(
    const float* __restrict__ Xg,             // [31][256][2048]
    const unsigned short* __restrict__ Whhb,  // [2048][512] bf16
    const unsigned short* __restrict__ Wlb,   // [10240][512] bf16
    const float* __restrict__ blin,           // [V_]
    unsigned short* __restrict__ HsAll,       // [32][256][512] bf16; slot0=h0
    int* __restrict__ cnt,                    // [32][8] arrival counters
    float* __restrict__ out) {                // [T*B_][V_] fp32
  __shared__ uint4 smem_raw[131072 / 16];     // 128 KB
  const int tid = threadIdx.x;
  const int w = tid >> 6, l = tid & 63;
  const int lr = l & 15;

  if (blockIdx.x < 64) {
    // ================= chain role =================
    unsigned short* hsh = (unsigned short*)smem_raw;           // [32][512] 32KB
    float* gsh = (float*)((char*)smem_raw + 32768);            // [4][32*64] 32KB
    const int gb = blockIdx.x & 7;
    const int ct = blockIdx.x >> 3;    // col tile 0..7 (64 cols)
    const int b0 = gb << 5;
    const int n0 = ct << 6;
    const int g  = w >> 1;             // gate 0..3
    const int cs = (w & 1) << 5;       // col-sub 0/32
    const int lk = (l >> 4) << 3;

    short8 bf0[16], bf1[16];
    {
      const unsigned short* wb0 = Whhb + (size_t)(g * 512 + n0 + cs + lr) * 512 + lk;
      const unsigned short* wb1 = wb0 + (size_t)16 * 512;
#pragma unroll 16
      for (int ks = 0; ks < 16; ++ks) {
        bf0[ks] = *(const short8*)(wb0 + (ks << 5));
        bf1[ks] = *(const short8*)(wb1 + (ks << 5));
      }
    }
    float c_reg[4] = {0.f, 0.f, 0.f, 0.f};
    const int br  = tid >> 4;
    const int nc0 = (tid & 15) << 2;
    const size_t xg_base = ((size_t)(b0 + br) << 11) + n0 + nc0;

    for (int t = 0; t < NSTEP; ++t) {
      const f32x4* xp = (const f32x4*)(Xg + (size_t)t * B_ * NG_ + xg_base);
      f32x4 xiv = xp[0], xfv = xp[128], xgv = xp[256], xov = xp[384];

      // gate on own group's step-t counter (t==0: h0 by stream order)
      if (t > 0) {
        int ok;
        do {
          int val = 1;
          if (tid == 0)
            val = (__hip_atomic_load(&cnt[t * 8 + gb], __ATOMIC_RELAXED,
                                     __HIP_MEMORY_SCOPE_AGENT) == 8);
          ok = __syncthreads_and(val);
          if (!ok) __builtin_amdgcn_s_sleep(2);
        } while (!ok);
      }

      // stage h_t rows b0..b0+31 via gload_lds, pre-swizzled source
#pragma unroll
      for (int j = 0; j < 4; ++j) {
        int row = (j << 3) + w;
        const unsigned short* gsrc = HsAll + (size_t)t * B_ * H_ +
                                     (size_t)(b0 + row) * 512 + ((l ^ (row & 7)) << 3);
        GLOAD_LDS16(gsrc, hsh + row * 512);
      }
      __syncthreads();

      f32x4 acc[2][2] = {};
#pragma unroll
      for (int ks = 0; ks < 16; ++ks) {
        int kc = (ks << 2) + (l >> 4);
        short8 a0 = *(const short8*)(hsh + lr * 512 + ((kc ^ (lr & 7)) << 3));
        short8 a1 = *(const short8*)(hsh + (16 + lr) * 512 + ((kc ^ (lr & 7)) << 3));
        acc[0][0] = __builtin_amdgcn_mfma_f32_16x16x32_bf16(a0, bf0[ks], acc[0][0], 0, 0, 0);
        acc[0][1] = __builtin_amdgcn_mfma_f32_16x16x32_bf16(a0, bf1[ks], acc[0][1], 0, 0, 0);
        acc[1][0] = __builtin_amdgcn_mfma_f32_16x16x32_bf16(a1, bf0[ks], acc[1][0], 0, 0, 0);
        acc[1][1] = __builtin_amdgcn_mfma_f32_16x16x32_bf16(a1, bf1[ks], acc[1][1], 0, 0, 0);
      }

      const int gr0 = (l >> 4) << 2;
#pragma unroll
      for (int m = 0; m < 2; ++m)
#pragma unroll
        for (int n = 0; n < 2; ++n)
#pragma unroll
          for (int r = 0; r < 4; ++r)
            gsh[g * 2048 + (m * 16 + gr0 + r) * 64 + cs + n * 16 + lr] = acc[m][n][r];
      __syncthreads();

      f32x4 giv = *(const f32x4*)&gsh[0 * 2048 + br * 64 + nc0];
      f32x4 gfv = *(const f32x4*)&gsh[1 * 2048 + br * 64 + nc0];
      f32x4 ggv = *(const f32x4*)&gsh[2 * 2048 + br * 64 + nc0];
      f32x4 gov = *(const f32x4*)&gsh[3 * 2048 + br * 64 + nc0];
      ushort4 hv; unsigned short* hvp = &hv.x;
#pragma unroll
      for (int j = 0; j < 4; ++j) {
        float is = fsig(giv[j] + xiv[j]);
        float fs = fsig(gfv[j] + xfv[j]);
        float os = fsig(gov[j] + xov[j]);
        float gt = ftanh_(ggv[j] + xgv[j]);
        float cn = fs * c_reg[j] + is * gt;
        c_reg[j] = cn;
        hvp[j] = f2bf(os * ftanh_(cn));
      }
      unsigned short* h_out = HsAll + (size_t)(t + 1) * B_ * H_;
      store8_cc(h_out + ((size_t)(b0 + br) << 9) + n0 + nc0,
                *reinterpret_cast<uint2*>(&hv));

      // publish: per-thread drain, barrier (all stores at coherence point),
      // then one relaxed counter add for slot t+1.
      asm volatile("s_waitcnt vmcnt(0)" ::: "memory");
      __syncthreads();
      if (tid == 0)
        __hip_atomic_fetch_add(&cnt[(t + 1) * 8 + gb], 1, __ATOMIC_RELAXED,
                               __HIP_MEMORY_SCOPE_AGENT);
    }
  } else {
    // ================= logits role =================
    unsigned short* As = (unsigned short*)smem_raw;            // 2x[256][64] 64KB
    unsigned short* Bs = (unsigned short*)((char*)smem_raw + 65536);
    const int idx = blockIdx.x - 64;
    const int t  = idx / 40 + 1;       // 1..31, ascending with blockIdx
    const int bn = idx % 40;

    // gate: all 8 groups of step t published (cheap 4B polls)
    {
      int ok;
      do {
        int val = 1;
        if (tid < 8)
          val = (__hip_atomic_load(&cnt[t * 8 + tid], __ATOMIC_RELAXED,
                                   __HIP_MEMORY_SCOPE_AGENT) == 8);
        ok = __syncthreads_and(val);
        if (!ok) __builtin_amdgcn_s_sleep(16);
      } while (!ok);
    }

    const unsigned short* slotT = HsAll + (size_t)t * B_ * H_;
    const int wr = w >> 2, wc = w & 3;
    const int srow = (w << 3) + (l >> 3);
    const int schunk = (l & 7) ^ ((l >> 3) & 7);
    const unsigned short* Ab = slotT + (size_t)srow * 512 + (schunk << 3);
    const unsigned short* Bb = Wlb + (size_t)(bn * 256 + srow) * 512 + (schunk << 3);
    unsigned short* Al = As + (w << 9);
    unsigned short* Bl = Bs + (w << 9);

    f32x4 acc[8][4] = {};
#pragma unroll
    for (int i = 0; i < 4; ++i) {
      GLOAD_LDS16(Ab + (size_t)(i << 6) * 512, Al + (i << 12));
      GLOAD_LDS16(Bb + (size_t)(i << 6) * 512, Bl + (i << 12));
    }
    asm volatile("s_waitcnt vmcnt(0)" ::: "memory");
    __syncthreads();

    for (int kt = 0; kt < 8; ++kt) {
      const int cur = (kt & 1) << 14;
      if (kt < 7) {
        const int nb = ((kt & 1) ^ 1) << 14;
        const int k0 = (kt + 1) << 6;
#pragma unroll
        for (int i = 0; i < 4; ++i) {
          GLOAD_LDS16(Ab + (size_t)(i << 6) * 512 + k0, Al + nb + (i << 12));
          GLOAD_LDS16(Bb + (size_t)(i << 6) * 512 + k0, Bl + nb + (i << 12));
        }
      }
      const unsigned short* ab = As + cur;
      const unsigned short* bb = Bs + cur;
#pragma unroll
      for (int kc = 0; kc < 2; ++kc) {
        const int cI = (kc << 2) + (l >> 4);
        const int rchunk = (cI ^ (lr & 7)) << 3;
        short8 af[8], bf8[4];
#pragma unroll
        for (int m = 0; m < 8; ++m)
          af[m] = *(const short8*)(ab + ((wr << 7) + (m << 4) + lr) * 64 + rchunk);
#pragma unroll
        for (int n = 0; n < 4; ++n)
          bf8[n] = *(const short8*)(bb + ((wc << 6) + (n << 4) + lr) * 64 + rchunk);
#pragma unroll
        for (int m = 0; m < 8; ++m)
#pragma unroll
          for (int n = 0; n < 4; ++n)
            acc[m][n] = __builtin_amdgcn_mfma_f32_16x16x32_bf16(af[m], bf8[n], acc[m][n], 0, 0, 0);
      }
      asm volatile("s_waitcnt vmcnt(0)" ::: "memory");
      __syncthreads();
    }

    const int orow0 = t * 256 + (wr << 7) + ((l >> 4) << 2);
    const int ocol0 = bn * 256 + (wc << 6) + lr;
#pragma unroll
    for (int n = 0; n < 4; ++n) {
      int col = ocol0 + (n << 4);
      if (col < V_) {
        float bv = blin[col];
#pragma unroll
        for (int m = 0; m < 8; ++m) {
          int row = orow0 + (m << 4);
#pragma unroll
          for (int r = 0; r < 4; ++r)
            __builtin_nontemporal_store(acc[m][n][r] + bv,
                &out[(size_t)(row + r) * V_ + col]);
        }
      }
    }
  }
}

extern "C" void kernel_launch(void* const* d_in, const int* in_sizes, int n_in,
                              void* d_out, int out_size, void* d_ws, size_t ws_size,
                              hipStream_t stream) {
  const int*   caps   = (const int*)d_in[0];
  const float* latent = (const float*)d_in[1];
  const float* embed  = (const float*)d_in[2];
  const float* Wih    = (const float*)d_in[3];
  const float* Whh    = (const float*)d_in[4];
  const float* bih    = (const float*)d_in[5];
  const float* bhh    = (const float*)d_in[6];
  const float* Wlin   = (const float*)d_in[7];
  const float* blin   = (const float*)d_in[8];
  float* out = (float*)d_out;

  char* ws = (char*)d_ws;
  size_t off = 0;
  auto alloc = [&](size_t bytes) {
    void* p = ws + off;
    off = (off + bytes + 255) & ~(size_t)255;
    return p;
  };
  unsigned short* Xbf   = (unsigned short*)alloc((size_t)M_ * E_ * 2);
  unsigned short* Wihb  = (unsigned short*)alloc((size_t)NG_ * E_ * 2);
  unsigned short* Whhb  = (unsigned short*)alloc((size_t)NG_ * H_ * 2);
  unsigned short* Wlb   = (unsigned short*)alloc((size_t)VPAD_ * H_ * 2);
  float*          bias  = (float*)alloc((size_t)NG_ * 4);
  float*          Xg    = (float*)alloc((size_t)M_ * NG_ * 4);
  unsigned short* HsAll = (unsigned short*)alloc((size_t)(NSTEP + 1) * B_ * H_ * 2);
  int*            cnt   = (int*)alloc((size_t)32 * 8 * 4);
  (void)ws_size; (void)in_sizes; (void)n_in; (void)out_size;

  hipLaunchKernelGGL(k_prep, dim3(2048), dim3(256), 0, stream,
                     Wih, Whh, Wlin, bih, bhh, Wihb, Whhb, Wlb, bias);
  hipLaunchKernelGGL(k_gather, dim3(2048), dim3(256), 0, stream,
                     caps, embed, latent, Xbf, HsAll, out, cnt);
  // Xg = X @ Wih^T + bias   [7936 x 2048]
  hipLaunchKernelGGL((gemm256<false>), dim3(NG_ / 256, M_ / 256), dim3(512), 0, stream,
                     Xbf, Wihb, bias, Xg, NG_, NG_);
  // mixed chain + logits kernel: 64 chain blocks (first, exclusive CUs at
  // 1 block/CU) + 31*40 logits tiles in t-ascending order.
  hipLaunchKernelGGL(k_mix, dim3(64 + NSTEP * 40), dim3(512), 0, stream,
                     Xg, Whhb, Wlb, blin, HsAll, cnt, out);
}